// Round 2
// baseline (494.250 us; speedup 1.0000x reference)
//
#include <hip/hip_runtime.h>
#include <hip/hip_fp16.h>
#include <math.h>

typedef _Float16 half8  __attribute__((ext_vector_type(8)));
typedef _Float16 half2v __attribute__((ext_vector_type(2)));
typedef float   floatx4 __attribute__((ext_vector_type(4)));

#define ROWS   16384
#define DIM    128
#define KCODES 8192
#define NSPLIT 8
#define MTILE  256
#define NT     64
#define NCHUNK ((KCODES / NSPLIT) / NT)   // 16

__device__ __forceinline__ void async_copy16(const _Float16* src, _Float16* dst_lds) {
  __builtin_amdgcn_global_load_lds((const __attribute__((address_space(1))) void*)src,
                                   (__attribute__((address_space(3))) void*)dst_lds,
                                   16, 0, 0);
}

// ---------------- kernel 1: codebook prep (fp16 hi/lo split + e2) ----------------
__global__ __launch_bounds__(256) void prep_codebook(
    const float* __restrict__ cb, _Float16* __restrict__ ehg,
    _Float16* __restrict__ elg, float* __restrict__ e2g)
{
  int tid = threadIdx.x;
  int L = tid & 63;
  int row = blockIdx.x * 4 + (tid >> 6);
  const float2* cr = (const float2*)(cb + (size_t)row * DIM);
  float2 v = cr[L];
  float s2 = v.x * v.x + v.y * v.y;
  #pragma unroll
  for (int m = 1; m < 64; m <<= 1) s2 += __shfl_xor(s2, m);
  if (L == 0) e2g[row] = s2;
  _Float16 h0 = (_Float16)v.x, h1 = (_Float16)v.y;
  half2v hi = {h0, h1};
  half2v lo = {(_Float16)(v.x - (float)h0), (_Float16)(v.y - (float)h1)};
  ((half2v*)(ehg + (size_t)row * DIM))[L] = hi;
  ((half2v*)(elg + (size_t)row * DIM))[L] = lo;
}

// ---------------- kernel 2: LN + argmin via split-fp16 MFMA ----------------
// block = 512 thr (8 waves); wave handles 32 rows (2 groups of 16) -> MTILE=256.
// Double-buffered LDS tile (64 codes hi+lo = 32 KB per buf), async global_load_lds,
// XOR-swizzled layout (swizzle folded into the SOURCE address so the lane-linear
// LDS write of global_load_lds lands in the right slot).
__global__ __launch_bounds__(512, 4) void argmin_kernel(
    const float* __restrict__ x, const _Float16* __restrict__ ehg,
    const _Float16* __restrict__ elg, const float* __restrict__ e2g,
    float* __restrict__ best_part, int* __restrict__ idx_part)
{
  // [buf][arr(hi/lo)][code n][128 halfs]; chunk kcs within a row holds global
  // chunk kc = kcs ^ (n&7)  (16B chunks). 64 KB total.
  __shared__ _Float16 ebuf[2][2][64][128];

  int tid = threadIdx.x;
  int w   = tid >> 6;
  int L   = tid & 63;
  int c   = L & 15;      // MFMA A-row / B-col lane index
  int q   = L >> 4;      // quad

  int bx = blockIdx.x;
  int mt = bx & (ROWS / MTILE - 1);   // 0..63
  int ns = bx >> 6;                   // 0..7

  int rowbase = mt * MTILE + w * 32;

  half8 ah[2][4], al[2][4];

  #pragma unroll
  for (int g = 0; g < 2; ++g) {
    const float* xr = x + (size_t)(rowbase + g * 16 + c) * DIM;
    float v[32];
    #pragma unroll
    for (int ks = 0; ks < 4; ++ks) {
      float4 p0 = *(const float4*)(xr + ks * 32 + q * 8);
      float4 p1 = *(const float4*)(xr + ks * 32 + q * 8 + 4);
      v[ks*8+0] = p0.x; v[ks*8+1] = p0.y; v[ks*8+2] = p0.z; v[ks*8+3] = p0.w;
      v[ks*8+4] = p1.x; v[ks*8+5] = p1.y; v[ks*8+6] = p1.z; v[ks*8+7] = p1.w;
    }
    float s = 0.f;
    #pragma unroll
    for (int i = 0; i < 32; ++i) s += v[i];
    s += __shfl_xor(s, 16); s += __shfl_xor(s, 32);
    float mu = s * (1.0f / 128.0f);
    float s2 = 0.f;
    #pragma unroll
    for (int i = 0; i < 32; ++i) { float d = v[i] - mu; s2 += d * d; }
    s2 += __shfl_xor(s2, 16); s2 += __shfl_xor(s2, 32);
    float rstd = 1.0f / sqrtf(s2 * (1.0f / 128.0f) + 1e-5f);
    #pragma unroll
    for (int ks = 0; ks < 4; ++ks)
      #pragma unroll
      for (int j = 0; j < 8; ++j) {
        float xv = (v[ks*8+j] - mu) * rstd;
        _Float16 h = (_Float16)xv;
        ah[g][ks][j] = h;
        al[g][ks][j] = (_Float16)(xv - (float)h);
      }
  }

  // score = e2 - 2*dot  (x^2 is constant per row -> does not affect argmin)
  float best[2][4]; int bidx[2][4];
  #pragma unroll
  for (int g = 0; g < 2; ++g)
    #pragma unroll
    for (int r = 0; r < 4; ++r) { best[g][r] = 3.4e38f; bidx[g][r] = 0; }

  int code0 = ns * (KCODES / NSPLIT);
  _Float16* lbase = &ebuf[0][0][0][0];

  // ---- async staging: 2048 16B chunks per tile, 4 per thread ----
  auto stage = [&](int ch, int p) {
    int cbase = code0 + ch * NT;
    _Float16* lb = lbase + (size_t)p * 2 * 64 * 128;
    #pragma unroll
    for (int it = 0; it < 4; ++it) {
      int cid = it * 512 + tid;          // 0..2047
      int arr = cid >> 10;               // 0 = hi, 1 = lo
      int lc  = cid & 1023;
      int n   = lc >> 4;
      int kcs = lc & 15;                 // LDS slot chunk
      int kc  = kcs ^ (n & 7);           // global chunk (inverse swizzle)
      const _Float16* g = (arr ? elg : ehg) + (size_t)(cbase + n) * DIM + kc * 8;
      async_copy16(g, lb + (size_t)cid * 8);
    }
  };

  stage(0, 0);
  __syncthreads();

  for (int ch = 0; ch < NCHUNK; ++ch) {
    int p = ch & 1;
    int cbase = code0 + ch * NT;
    if (ch + 1 < NCHUNK) stage(ch + 1, p ^ 1);

    float e2v[4];
    #pragma unroll
    for (int s = 0; s < 4; ++s) e2v[s] = e2g[cbase + s * 16 + c];

    #pragma unroll
    for (int s = 0; s < 4; ++s) {
      int n = s * 16 + c;                // n & 7 == c & 7
      half8 bh[4], bl[4];
      #pragma unroll
      for (int ks = 0; ks < 4; ++ks) {
        int slot = ((ks * 4 + q) ^ (c & 7)) * 8;
        bh[ks] = *(const half8*)&ebuf[p][0][n][slot];
        bl[ks] = *(const half8*)&ebuf[p][1][n][slot];
      }
      int nn = cbase + n;
      #pragma unroll
      for (int g = 0; g < 2; ++g) {
        floatx4 hh = {0.f,0.f,0.f,0.f}, hl = {0.f,0.f,0.f,0.f}, lh = {0.f,0.f,0.f,0.f};
        #pragma unroll
        for (int ks = 0; ks < 4; ++ks) {
          hh = __builtin_amdgcn_mfma_f32_16x16x32_f16(ah[g][ks], bh[ks], hh, 0, 0, 0);
          hl = __builtin_amdgcn_mfma_f32_16x16x32_f16(ah[g][ks], bl[ks], hl, 0, 0, 0);
          lh = __builtin_amdgcn_mfma_f32_16x16x32_f16(al[g][ks], bh[ks], lh, 0, 0, 0);
        }
        #pragma unroll
        for (int r = 0; r < 4; ++r) {
          float dot = (hh[r] + hl[r]) + lh[r];
          float score = fmaf(-2.0f, dot, e2v[s]);
          if (score < best[g][r]) { best[g][r] = score; bidx[g][r] = nn; }
        }
      }
    }
    __syncthreads();   // drains async stage of ch+1; protects buf reuse
  }

  // reduce over the 16 col-lanes of each quad; ties -> smaller index
  #pragma unroll
  for (int m = 1; m < 16; m <<= 1)
    #pragma unroll
    for (int g = 0; g < 2; ++g)
      #pragma unroll
      for (int r = 0; r < 4; ++r) {
        float ob = __shfl_xor(best[g][r], m);
        int   oi = __shfl_xor(bidx[g][r], m);
        if (ob < best[g][r] || (ob == best[g][r] && oi < bidx[g][r])) {
          best[g][r] = ob; bidx[g][r] = oi;
        }
      }
  if (c == 0) {
    #pragma unroll
    for (int g = 0; g < 2; ++g)
      #pragma unroll
      for (int r = 0; r < 4; ++r) {
        int row = rowbase + g * 16 + q * 4 + r;
        best_part[(size_t)row * NSPLIT + ns] = best[g][r];
        idx_part [(size_t)row * NSPLIT + ns] = bidx[g][r];
      }
  }
}

// ---------------- kernel 3: merge splits + gather + per-row loss ----------------
__global__ __launch_bounds__(256) void gather_loss_kernel(
    const float* __restrict__ x, const float* __restrict__ cb,
    const float* __restrict__ best_part, const int* __restrict__ idx_part,
    float* __restrict__ out_q, float* __restrict__ out_ind,
    float* __restrict__ row_loss)
{
  int tid = threadIdx.x;
  int L = tid & 63;
  int row = blockIdx.x * 4 + (tid >> 6);

  // merge 8 partials (lanes load broadcast copies; xor-reduce over 8-groups)
  float b  = best_part[(size_t)row * NSPLIT + (L & 7)];
  int   bi = idx_part [(size_t)row * NSPLIT + (L & 7)];
  #pragma unroll
  for (int m = 1; m < 8; m <<= 1) {
    float ob = __shfl_xor(b, m);
    int   oi = __shfl_xor(bi, m);
    if (ob < b || (ob == b && oi < bi)) { b = ob; bi = oi; }
  }

  float2 qv = ((const float2*)(cb + (size_t)bi * DIM))[L];
  float2 xv = ((const float2*)(x  + (size_t)row * DIM))[L];
  float s = xv.x + xv.y;
  #pragma unroll
  for (int m = 1; m < 64; m <<= 1) s += __shfl_xor(s, m);
  float mu = s * (1.0f / 128.0f);
  float dx = xv.x - mu, dy = xv.y - mu;
  float s2 = dx * dx + dy * dy;
  #pragma unroll
  for (int m = 1; m < 64; m <<= 1) s2 += __shfl_xor(s2, m);
  float rstd = 1.0f / sqrtf(s2 * (1.0f / 128.0f) + 1e-5f);
  float xn0 = dx * rstd, xn1 = dy * rstd;
  ((float2*)out_q)[(size_t)row * 64 + L] = qv;
  float e0 = qv.x - xn0, e1 = qv.y - xn1;
  float le = e0 * e0 + e1 * e1;
  #pragma unroll
  for (int m = 1; m < 64; m <<= 1) le += __shfl_xor(le, m);
  if (L == 0) {
    row_loss[row] = le;
    out_ind[row] = (float)bi;
  }
}

// ---------------- kernel 4: deterministic loss reduction ----------------
__global__ __launch_bounds__(1024) void loss_reduce_kernel(
    const float* __restrict__ row_loss, float* __restrict__ out_loss)
{
  __shared__ float sm[1024];
  int tid = threadIdx.x;
  float s = 0.f;
  for (int i = tid; i < ROWS; i += 1024) s += row_loss[i];
  sm[tid] = s; __syncthreads();
  for (int st = 512; st > 0; st >>= 1) {
    if (tid < st) sm[tid] += sm[tid + st];
    __syncthreads();
  }
  if (tid == 0) *out_loss = sm[0] * (1.0f / (float)(ROWS * DIM));
}

extern "C" void kernel_launch(void* const* d_in, const int* in_sizes, int n_in,
                              void* d_out, int out_size, void* d_ws, size_t ws_size,
                              hipStream_t stream)
{
  const float* x  = (const float*)d_in[0];   // [4,4096,128] fp32
  const float* cb = (const float*)d_in[1];   // [8192,128]  fp32

  char* ws = (char*)d_ws;
  _Float16* ehg      = (_Float16*)(ws + 0);          // 2 MB
  _Float16* elg      = (_Float16*)(ws + 2097152);    // 2 MB
  float*    e2g      = (float*)   (ws + 4194304);    // 32 KB
  float*    best_part= (float*)   (ws + 4227072);    // 512 KB
  int*      idx_part = (int*)     (ws + 4751360);    // 512 KB
  float*    row_loss = (float*)   (ws + 5275648);    // 64 KB

  float* out_q    = (float*)d_out;                   // 16384*128
  float* out_ind  = out_q + (size_t)ROWS * DIM;      // 16384 (as float)
  float* out_loss = out_ind + ROWS;                  // 1

  prep_codebook<<<KCODES / 4, 256, 0, stream>>>(cb, ehg, elg, e2g);
  argmin_kernel<<<(ROWS / MTILE) * NSPLIT, 512, 0, stream>>>(x, ehg, elg, e2g, best_part, idx_part);
  gather_loss_kernel<<<ROWS / 4, 256, 0, stream>>>(x, cb, best_part, idx_part, out_q, out_ind, row_loss);
  loss_reduce_kernel<<<1, 1024, 0, stream>>>(row_loss, out_loss);
}

// Round 3
// 164.101 us; speedup vs baseline: 3.0119x; 3.0119x over previous
//
#include <hip/hip_runtime.h>
#include <hip/hip_fp16.h>
#include <math.h>

typedef _Float16 half8  __attribute__((ext_vector_type(8)));
typedef _Float16 half2v __attribute__((ext_vector_type(2)));
typedef float   floatx4 __attribute__((ext_vector_type(4)));

#define ROWS   16384
#define DIM    128
#define KCODES 8192
#define NSPLIT 4
#define MTILE  256
#define NT     64
#define NCHUNK ((KCODES / NSPLIT) / NT)   // 32

__device__ __forceinline__ void async_copy16(const _Float16* src, _Float16* dst_lds) {
  __builtin_amdgcn_global_load_lds((const __attribute__((address_space(1))) void*)src,
                                   (__attribute__((address_space(3))) void*)dst_lds,
                                   16, 0, 0);
}

// ---------------- kernel 1: codebook prep (fp16 hi/lo split + e2) ----------------
__global__ __launch_bounds__(256) void prep_codebook(
    const float* __restrict__ cb, _Float16* __restrict__ ehg,
    _Float16* __restrict__ elg, float* __restrict__ e2g)
{
  int tid = threadIdx.x;
  int L = tid & 63;
  int row = blockIdx.x * 4 + (tid >> 6);
  const float2* cr = (const float2*)(cb + (size_t)row * DIM);
  float2 v = cr[L];
  float s2 = v.x * v.x + v.y * v.y;
  #pragma unroll
  for (int m = 1; m < 64; m <<= 1) s2 += __shfl_xor(s2, m);
  if (L == 0) e2g[row] = s2;
  _Float16 h0 = (_Float16)v.x, h1 = (_Float16)v.y;
  half2v hi = {h0, h1};
  half2v lo = {(_Float16)(v.x - (float)h0), (_Float16)(v.y - (float)h1)};
  ((half2v*)(ehg + (size_t)row * DIM))[L] = hi;
  ((half2v*)(elg + (size_t)row * DIM))[L] = lo;
}

// ---------------- kernel 2: LN + argmin via split-fp16 MFMA ----------------
// block = 512 thr (8 waves); wave handles 32 rows (2 groups of 16) -> MTILE=256.
// Double-buffered LDS (2 x 32 KB), async global_load_lds width-16, XOR-swizzled
// layout folded into the SOURCE address (lane-linear LDS writes land correctly).
// NOTE: __launch_bounds__ 2nd arg acts as min BLOCKS/CU on this toolchain
// (round-2 evidence: (512,4) -> 64-VGPR cap -> 1.8 GB scratch spill traffic).
// (512,1) -> 256-VGPR cap -> no spills; ~1 block/CU, 6 indep MFMA chains/wave.
__global__ __launch_bounds__(512, 1) void argmin_kernel(
    const float* __restrict__ x, const _Float16* __restrict__ ehg,
    const _Float16* __restrict__ elg, const float* __restrict__ e2g,
    float* __restrict__ best_part, int* __restrict__ idx_part)
{
  // [buf][arr(hi/lo)][code n][128 halfs]; chunk kcs within a row holds global
  // chunk kc = kcs ^ (n&7)  (16B chunks). 64 KB total.
  __shared__ _Float16 ebuf[2][2][64][128];

  int tid = threadIdx.x;
  int w   = tid >> 6;
  int L   = tid & 63;
  int c   = L & 15;      // MFMA A-row / B-col lane index
  int q   = L >> 4;      // quad

  int bx = blockIdx.x;
  int mt = bx & (ROWS / MTILE - 1);   // 0..63
  int ns = bx >> 6;                   // 0..3

  int rowbase = mt * MTILE + w * 32;

  half8 ah[2][4], al[2][4];

  #pragma unroll
  for (int g = 0; g < 2; ++g) {
    const float* xr = x + (size_t)(rowbase + g * 16 + c) * DIM;
    float v[32];
    #pragma unroll
    for (int ks = 0; ks < 4; ++ks) {
      float4 p0 = *(const float4*)(xr + ks * 32 + q * 8);
      float4 p1 = *(const float4*)(xr + ks * 32 + q * 8 + 4);
      v[ks*8+0] = p0.x; v[ks*8+1] = p0.y; v[ks*8+2] = p0.z; v[ks*8+3] = p0.w;
      v[ks*8+4] = p1.x; v[ks*8+5] = p1.y; v[ks*8+6] = p1.z; v[ks*8+7] = p1.w;
    }
    float s = 0.f;
    #pragma unroll
    for (int i = 0; i < 32; ++i) s += v[i];
    s += __shfl_xor(s, 16); s += __shfl_xor(s, 32);
    float mu = s * (1.0f / 128.0f);
    float s2 = 0.f;
    #pragma unroll
    for (int i = 0; i < 32; ++i) { float d = v[i] - mu; s2 += d * d; }
    s2 += __shfl_xor(s2, 16); s2 += __shfl_xor(s2, 32);
    float rstd = 1.0f / sqrtf(s2 * (1.0f / 128.0f) + 1e-5f);
    #pragma unroll
    for (int ks = 0; ks < 4; ++ks)
      #pragma unroll
      for (int j = 0; j < 8; ++j) {
        float xv = (v[ks*8+j] - mu) * rstd;
        _Float16 h = (_Float16)xv;
        ah[g][ks][j] = h;
        al[g][ks][j] = (_Float16)(xv - (float)h);
      }
  }

  // score = e2 - 2*dot  (x^2 is constant per row -> does not affect argmin)
  float best[2][4]; int bidx[2][4];
  #pragma unroll
  for (int g = 0; g < 2; ++g)
    #pragma unroll
    for (int r = 0; r < 4; ++r) { best[g][r] = 3.4e38f; bidx[g][r] = 0; }

  int code0 = ns * (KCODES / NSPLIT);
  _Float16* lbase = &ebuf[0][0][0][0];

  // ---- async staging: 2048 16B chunks per tile, 4 per thread ----
  auto stage = [&](int ch, int p) {
    int cbase = code0 + ch * NT;
    _Float16* lb = lbase + (size_t)p * 2 * 64 * 128;
    #pragma unroll
    for (int it = 0; it < 4; ++it) {
      int cid = it * 512 + tid;          // 0..2047
      int arr = cid >> 10;               // 0 = hi, 1 = lo
      int lc  = cid & 1023;
      int n   = lc >> 4;
      int kcs = lc & 15;                 // LDS slot chunk
      int kc  = kcs ^ (n & 7);           // global chunk (inverse swizzle)
      const _Float16* g = (arr ? elg : ehg) + (size_t)(cbase + n) * DIM + kc * 8;
      async_copy16(g, lb + (size_t)cid * 8);
    }
  };

  stage(0, 0);
  __syncthreads();

  for (int ch = 0; ch < NCHUNK; ++ch) {
    int p = ch & 1;
    int cbase = code0 + ch * NT;
    if (ch + 1 < NCHUNK) stage(ch + 1, p ^ 1);

    float e2v[4];
    #pragma unroll
    for (int s = 0; s < 4; ++s) e2v[s] = e2g[cbase + s * 16 + c];

    #pragma unroll
    for (int s = 0; s < 4; ++s) {
      int n = s * 16 + c;                // n & 7 == c & 7
      half8 bh[4], bl[4];
      #pragma unroll
      for (int ks = 0; ks < 4; ++ks) {
        int slot = ((ks * 4 + q) ^ (c & 7)) * 8;
        bh[ks] = *(const half8*)&ebuf[p][0][n][slot];
        bl[ks] = *(const half8*)&ebuf[p][1][n][slot];
      }
      int nn = cbase + n;
      #pragma unroll
      for (int g = 0; g < 2; ++g) {
        floatx4 hh = {0.f,0.f,0.f,0.f}, hl = {0.f,0.f,0.f,0.f}, lh = {0.f,0.f,0.f,0.f};
        #pragma unroll
        for (int ks = 0; ks < 4; ++ks) {
          hh = __builtin_amdgcn_mfma_f32_16x16x32_f16(ah[g][ks], bh[ks], hh, 0, 0, 0);
          hl = __builtin_amdgcn_mfma_f32_16x16x32_f16(ah[g][ks], bl[ks], hl, 0, 0, 0);
          lh = __builtin_amdgcn_mfma_f32_16x16x32_f16(al[g][ks], bh[ks], lh, 0, 0, 0);
        }
        #pragma unroll
        for (int r = 0; r < 4; ++r) {
          float dot = (hh[r] + hl[r]) + lh[r];
          float score = fmaf(-2.0f, dot, e2v[s]);
          if (score < best[g][r]) { best[g][r] = score; bidx[g][r] = nn; }
        }
      }
    }
    __syncthreads();   // drains async stage of ch+1; protects buf reuse
  }

  // reduce over the 16 col-lanes of each quad; ties -> smaller index
  #pragma unroll
  for (int m = 1; m < 16; m <<= 1)
    #pragma unroll
    for (int g = 0; g < 2; ++g)
      #pragma unroll
      for (int r = 0; r < 4; ++r) {
        float ob = __shfl_xor(best[g][r], m);
        int   oi = __shfl_xor(bidx[g][r], m);
        if (ob < best[g][r] || (ob == best[g][r] && oi < bidx[g][r])) {
          best[g][r] = ob; bidx[g][r] = oi;
        }
      }
  if (c == 0) {
    #pragma unroll
    for (int g = 0; g < 2; ++g)
      #pragma unroll
      for (int r = 0; r < 4; ++r) {
        int row = rowbase + g * 16 + q * 4 + r;
        best_part[(size_t)row * NSPLIT + ns] = best[g][r];
        idx_part [(size_t)row * NSPLIT + ns] = bidx[g][r];
      }
  }
}

// ---------------- kernel 3: merge splits + gather + per-row loss ----------------
__global__ __launch_bounds__(256) void gather_loss_kernel(
    const float* __restrict__ x, const float* __restrict__ cb,
    const float* __restrict__ best_part, const int* __restrict__ idx_part,
    float* __restrict__ out_q, float* __restrict__ out_ind,
    float* __restrict__ row_loss)
{
  int tid = threadIdx.x;
  int L = tid & 63;
  int row = blockIdx.x * 4 + (tid >> 6);

  // merge 4 partials (lanes load broadcast copies; xor-reduce over 4-groups)
  float b  = best_part[(size_t)row * NSPLIT + (L & 3)];
  int   bi = idx_part [(size_t)row * NSPLIT + (L & 3)];
  #pragma unroll
  for (int m = 1; m < 4; m <<= 1) {
    float ob = __shfl_xor(b, m);
    int   oi = __shfl_xor(bi, m);
    if (ob < b || (ob == b && oi < bi)) { b = ob; bi = oi; }
  }

  float2 qv = ((const float2*)(cb + (size_t)bi * DIM))[L];
  float2 xv = ((const float2*)(x  + (size_t)row * DIM))[L];
  float s = xv.x + xv.y;
  #pragma unroll
  for (int m = 1; m < 64; m <<= 1) s += __shfl_xor(s, m);
  float mu = s * (1.0f / 128.0f);
  float dx = xv.x - mu, dy = xv.y - mu;
  float s2 = dx * dx + dy * dy;
  #pragma unroll
  for (int m = 1; m < 64; m <<= 1) s2 += __shfl_xor(s2, m);
  float rstd = 1.0f / sqrtf(s2 * (1.0f / 128.0f) + 1e-5f);
  float xn0 = dx * rstd, xn1 = dy * rstd;
  ((float2*)out_q)[(size_t)row * 64 + L] = qv;
  float e0 = qv.x - xn0, e1 = qv.y - xn1;
  float le = e0 * e0 + e1 * e1;
  #pragma unroll
  for (int m = 1; m < 64; m <<= 1) le += __shfl_xor(le, m);
  if (L == 0) {
    row_loss[row] = le;
    out_ind[row] = (float)bi;
  }
}

// ---------------- kernel 4: deterministic loss reduction ----------------
__global__ __launch_bounds__(1024) void loss_reduce_kernel(
    const float* __restrict__ row_loss, float* __restrict__ out_loss)
{
  __shared__ float sm[1024];
  int tid = threadIdx.x;
  float s = 0.f;
  for (int i = tid; i < ROWS; i += 1024) s += row_loss[i];
  sm[tid] = s; __syncthreads();
  for (int st = 512; st > 0; st >>= 1) {
    if (tid < st) sm[tid] += sm[tid + st];
    __syncthreads();
  }
  if (tid == 0) *out_loss = sm[0] * (1.0f / (float)(ROWS * DIM));
}

extern "C" void kernel_launch(void* const* d_in, const int* in_sizes, int n_in,
                              void* d_out, int out_size, void* d_ws, size_t ws_size,
                              hipStream_t stream)
{
  const float* x  = (const float*)d_in[0];   // [4,4096,128] fp32
  const float* cb = (const float*)d_in[1];   // [8192,128]  fp32

  char* ws = (char*)d_ws;
  _Float16* ehg      = (_Float16*)(ws + 0);          // 2 MB
  _Float16* elg      = (_Float16*)(ws + 2097152);    // 2 MB
  float*    e2g      = (float*)   (ws + 4194304);    // 32 KB
  float*    best_part= (float*)   (ws + 4227072);    // 256 KB
  int*      idx_part = (int*)     (ws + 4489216);    // 256 KB
  float*    row_loss = (float*)   (ws + 4751360);    // 64 KB

  float* out_q    = (float*)d_out;                   // 16384*128
  float* out_ind  = out_q + (size_t)ROWS * DIM;      // 16384 (as float)
  float* out_loss = out_ind + ROWS;                  // 1

  prep_codebook<<<KCODES / 4, 256, 0, stream>>>(cb, ehg, elg, e2g);
  argmin_kernel<<<(ROWS / MTILE) * NSPLIT, 512, 0, stream>>>(x, ehg, elg, e2g, best_part, idx_part);
  gather_loss_kernel<<<ROWS / 4, 256, 0, stream>>>(x, cb, best_part, idx_part, out_q, out_ind, row_loss);
  loss_reduce_kernel<<<1, 1024, 0, stream>>>(row_loss, out_loss);
}

// Round 4
// 159.882 us; speedup vs baseline: 3.0913x; 1.0264x over previous
//
#include <hip/hip_runtime.h>
#include <hip/hip_fp16.h>
#include <math.h>

typedef _Float16 half8  __attribute__((ext_vector_type(8)));
typedef _Float16 half2v __attribute__((ext_vector_type(2)));
typedef float   floatx4 __attribute__((ext_vector_type(4)));

#define ROWS   16384
#define DIM    128
#define KCODES 8192
#define NSPLIT 8
#define MTILE  512
#define NT     64
#define NCHUNK ((KCODES / NSPLIT) / NT)   // 16

__device__ __forceinline__ void async_copy16(const _Float16* src, _Float16* dst_lds) {
  __builtin_amdgcn_global_load_lds((const __attribute__((address_space(1))) void*)src,
                                   (__attribute__((address_space(3))) void*)dst_lds,
                                   16, 0, 0);
}

// ---------------- kernel 1: codebook prep (fp16 hi/lo split + e2) ----------------
__global__ __launch_bounds__(256) void prep_codebook(
    const float* __restrict__ cb, _Float16* __restrict__ ehg,
    _Float16* __restrict__ elg, float* __restrict__ e2g)
{
  int tid = threadIdx.x;
  int L = tid & 63;
  int row = blockIdx.x * 4 + (tid >> 6);
  const float2* cr = (const float2*)(cb + (size_t)row * DIM);
  float2 v = cr[L];
  float s2 = v.x * v.x + v.y * v.y;
  #pragma unroll
  for (int m = 1; m < 64; m <<= 1) s2 += __shfl_xor(s2, m);
  if (L == 0) e2g[row] = s2;
  _Float16 h0 = (_Float16)v.x, h1 = (_Float16)v.y;
  half2v hi = {h0, h1};
  half2v lo = {(_Float16)(v.x - (float)h0), (_Float16)(v.y - (float)h1)};
  ((half2v*)(ehg + (size_t)row * DIM))[L] = hi;
  ((half2v*)(elg + (size_t)row * DIM))[L] = lo;
}

// ---------------- kernel 2: LN + argmin via split-fp16 MFMA ----------------
// block = 512 (8 waves); wave handles 64 rows (4 groups of 16) -> MTILE=512.
// B-fragments get 4x register reuse per LDS read (halves LDS traffic/MFMA).
// argmin(x^2-2dot+e2) == argmax(dot - e2/2): acc initialized to -e2/2, all 12
// MFMAs chained into one accumulator; epilogue is cmp+2csel per element.
// __launch_bounds__ 2nd arg acts as min BLOCKS/CU here (round-2 evidence:
// (512,4) -> 64-VGPR cap -> spills). Keep (512,1) -> 256-VGPR cap.
__global__ __launch_bounds__(512, 1) void argmin_kernel(
    const float* __restrict__ x, const _Float16* __restrict__ ehg,
    const _Float16* __restrict__ elg, const float* __restrict__ e2g,
    float* __restrict__ best_part, int* __restrict__ idx_part)
{
  // [buf][arr(hi/lo)][code n][128 halfs]; chunk kcs within a row holds global
  // chunk kc = kcs ^ (n&7)  (16B chunks). 64 KB total.
  __shared__ _Float16 ebuf[2][2][64][128];

  int tid = threadIdx.x;
  int w   = tid >> 6;
  int L   = tid & 63;
  int c   = L & 15;      // MFMA A-row / B-col lane index
  int q   = L >> 4;      // quad

  int bx = blockIdx.x;
  int mt = bx & (ROWS / MTILE - 1);   // 0..31
  int ns = bx >> 5;                   // 0..7

  int rowbase = mt * MTILE + w * 64;

  half8 ah[4][4], al[4][4];

  #pragma unroll
  for (int g = 0; g < 4; ++g) {
    const float* xr = x + (size_t)(rowbase + g * 16 + c) * DIM;
    float v[32];
    #pragma unroll
    for (int ks = 0; ks < 4; ++ks) {
      float4 p0 = *(const float4*)(xr + ks * 32 + q * 8);
      float4 p1 = *(const float4*)(xr + ks * 32 + q * 8 + 4);
      v[ks*8+0] = p0.x; v[ks*8+1] = p0.y; v[ks*8+2] = p0.z; v[ks*8+3] = p0.w;
      v[ks*8+4] = p1.x; v[ks*8+5] = p1.y; v[ks*8+6] = p1.z; v[ks*8+7] = p1.w;
    }
    float s = 0.f;
    #pragma unroll
    for (int i = 0; i < 32; ++i) s += v[i];
    s += __shfl_xor(s, 16); s += __shfl_xor(s, 32);
    float mu = s * (1.0f / 128.0f);
    float s2 = 0.f;
    #pragma unroll
    for (int i = 0; i < 32; ++i) { float d = v[i] - mu; s2 += d * d; }
    s2 += __shfl_xor(s2, 16); s2 += __shfl_xor(s2, 32);
    float rstd = 1.0f / sqrtf(s2 * (1.0f / 128.0f) + 1e-5f);
    #pragma unroll
    for (int ks = 0; ks < 4; ++ks)
      #pragma unroll
      for (int j = 0; j < 8; ++j) {
        float xv = (v[ks*8+j] - mu) * rstd;
        _Float16 h = (_Float16)xv;
        ah[g][ks][j] = h;
        al[g][ks][j] = (_Float16)(xv - (float)h);
      }
  }

  // track t = dot - e2/2 (maximize); ties -> smaller index
  float best[4][4]; int bidx[4][4];
  #pragma unroll
  for (int g = 0; g < 4; ++g)
    #pragma unroll
    for (int r = 0; r < 4; ++r) { best[g][r] = -3.4e38f; bidx[g][r] = 0; }

  int code0 = ns * (KCODES / NSPLIT);
  _Float16* lbase = &ebuf[0][0][0][0];

  // ---- async staging: 2048 16B chunks per tile, 4 per thread ----
  auto stage = [&](int ch, int p) {
    int cbase = code0 + ch * NT;
    _Float16* lb = lbase + (size_t)p * 2 * 64 * 128;
    #pragma unroll
    for (int it = 0; it < 4; ++it) {
      int cid = it * 512 + tid;          // 0..2047
      int arr = cid >> 10;               // 0 = hi, 1 = lo
      int lc  = cid & 1023;
      int n   = lc >> 4;
      int kcs = lc & 15;                 // LDS slot chunk
      int kc  = kcs ^ (n & 7);           // global chunk (inverse swizzle)
      const _Float16* g = (arr ? elg : ehg) + (size_t)(cbase + n) * DIM + kc * 8;
      async_copy16(g, lb + (size_t)cid * 8);
    }
  };

  stage(0, 0);
  __syncthreads();

  for (int ch = 0; ch < NCHUNK; ++ch) {
    int p = ch & 1;
    int cbase = code0 + ch * NT;
    if (ch + 1 < NCHUNK) stage(ch + 1, p ^ 1);

    float e2h[4];
    #pragma unroll
    for (int s = 0; s < 4; ++s) e2h[s] = -0.5f * e2g[cbase + s * 16 + c];

    #pragma unroll
    for (int s = 0; s < 4; ++s) {
      int n = s * 16 + c;                // n & 7 == c & 7
      half8 bh[4], bl[4];
      #pragma unroll
      for (int ks = 0; ks < 4; ++ks) {
        int slot = ((ks * 4 + q) ^ (c & 7)) * 8;
        bh[ks] = *(const half8*)&ebuf[p][0][n][slot];
        bl[ks] = *(const half8*)&ebuf[p][1][n][slot];
      }
      int nn = cbase + n;
      #pragma unroll
      for (int g = 0; g < 4; ++g) {
        floatx4 acc = {e2h[s], e2h[s], e2h[s], e2h[s]};
        #pragma unroll
        for (int ks = 0; ks < 4; ++ks) {
          acc = __builtin_amdgcn_mfma_f32_16x16x32_f16(ah[g][ks], bh[ks], acc, 0, 0, 0);
          acc = __builtin_amdgcn_mfma_f32_16x16x32_f16(ah[g][ks], bl[ks], acc, 0, 0, 0);
          acc = __builtin_amdgcn_mfma_f32_16x16x32_f16(al[g][ks], bh[ks], acc, 0, 0, 0);
        }
        #pragma unroll
        for (int r = 0; r < 4; ++r) {
          float t = acc[r];
          if (t > best[g][r]) { best[g][r] = t; bidx[g][r] = nn; }
        }
      }
    }
    __syncthreads();   // drains async stage of ch+1; protects buf reuse
  }

  // reduce over the 16 col-lanes of each quad; max-t, ties -> smaller index
  #pragma unroll
  for (int m = 1; m < 16; m <<= 1)
    #pragma unroll
    for (int g = 0; g < 4; ++g)
      #pragma unroll
      for (int r = 0; r < 4; ++r) {
        float ob = __shfl_xor(best[g][r], m);
        int   oi = __shfl_xor(bidx[g][r], m);
        if (ob > best[g][r] || (ob == best[g][r] && oi < bidx[g][r])) {
          best[g][r] = ob; bidx[g][r] = oi;
        }
      }
  if (c == 0) {
    #pragma unroll
    for (int g = 0; g < 4; ++g)
      #pragma unroll
      for (int r = 0; r < 4; ++r) {
        int row = rowbase + g * 16 + q * 4 + r;
        best_part[(size_t)row * NSPLIT + ns] = best[g][r];
        idx_part [(size_t)row * NSPLIT + ns] = bidx[g][r];
      }
  }
}

// ---------------- kernel 3: merge splits + gather + per-row loss ----------------
__global__ __launch_bounds__(256) void gather_loss_kernel(
    const float* __restrict__ x, const float* __restrict__ cb,
    const float* __restrict__ best_part, const int* __restrict__ idx_part,
    float* __restrict__ out_q, float* __restrict__ out_ind,
    float* __restrict__ row_loss)
{
  int tid = threadIdx.x;
  int L = tid & 63;
  int row = blockIdx.x * 4 + (tid >> 6);

  // merge 8 partials (max-t, ties -> smaller index)
  float b  = best_part[(size_t)row * NSPLIT + (L & 7)];
  int   bi = idx_part [(size_t)row * NSPLIT + (L & 7)];
  #pragma unroll
  for (int m = 1; m < 8; m <<= 1) {
    float ob = __shfl_xor(b, m);
    int   oi = __shfl_xor(bi, m);
    if (ob > b || (ob == b && oi < bi)) { b = ob; bi = oi; }
  }

  float2 qv = ((const float2*)(cb + (size_t)bi * DIM))[L];
  float2 xv = ((const float2*)(x  + (size_t)row * DIM))[L];
  float s = xv.x + xv.y;
  #pragma unroll
  for (int m = 1; m < 64; m <<= 1) s += __shfl_xor(s, m);
  float mu = s * (1.0f / 128.0f);
  float dx = xv.x - mu, dy = xv.y - mu;
  float s2 = dx * dx + dy * dy;
  #pragma unroll
  for (int m = 1; m < 64; m <<= 1) s2 += __shfl_xor(s2, m);
  float rstd = 1.0f / sqrtf(s2 * (1.0f / 128.0f) + 1e-5f);
  float xn0 = dx * rstd, xn1 = dy * rstd;
  ((float2*)out_q)[(size_t)row * 64 + L] = qv;
  float e0 = qv.x - xn0, e1 = qv.y - xn1;
  float le = e0 * e0 + e1 * e1;
  #pragma unroll
  for (int m = 1; m < 64; m <<= 1) le += __shfl_xor(le, m);
  if (L == 0) {
    row_loss[row] = le;
    out_ind[row] = (float)bi;
  }
}

// ---------------- kernel 4: deterministic loss reduction ----------------
__global__ __launch_bounds__(1024) void loss_reduce_kernel(
    const float* __restrict__ row_loss, float* __restrict__ out_loss)
{
  __shared__ float sm[1024];
  int tid = threadIdx.x;
  float s = 0.f;
  for (int i = tid; i < ROWS; i += 1024) s += row_loss[i];
  sm[tid] = s; __syncthreads();
  for (int st = 512; st > 0; st >>= 1) {
    if (tid < st) sm[tid] += sm[tid + st];
    __syncthreads();
  }
  if (tid == 0) *out_loss = sm[0] * (1.0f / (float)(ROWS * DIM));
}

extern "C" void kernel_launch(void* const* d_in, const int* in_sizes, int n_in,
                              void* d_out, int out_size, void* d_ws, size_t ws_size,
                              hipStream_t stream)
{
  const float* x  = (const float*)d_in[0];   // [4,4096,128] fp32
  const float* cb = (const float*)d_in[1];   // [8192,128]  fp32

  char* ws = (char*)d_ws;
  _Float16* ehg      = (_Float16*)(ws + 0);          // 2 MB
  _Float16* elg      = (_Float16*)(ws + 2097152);    // 2 MB
  float*    e2g      = (float*)   (ws + 4194304);    // 32 KB
  float*    best_part= (float*)   (ws + 4227072);    // 512 KB
  int*      idx_part = (int*)     (ws + 4751360);    // 512 KB
  float*    row_loss = (float*)   (ws + 5275648);    // 64 KB

  float* out_q    = (float*)d_out;                   // 16384*128
  float* out_ind  = out_q + (size_t)ROWS * DIM;      // 16384 (as float)
  float* out_loss = out_ind + ROWS;                  // 1

  prep_codebook<<<KCODES / 4, 256, 0, stream>>>(cb, ehg, elg, e2g);
  argmin_kernel<<<(ROWS / MTILE) * NSPLIT, 512, 0, stream>>>(x, ehg, elg, e2g, best_part, idx_part);
  gather_loss_kernel<<<ROWS / 4, 256, 0, stream>>>(x, cb, best_part, idx_part, out_q, out_ind, row_loss);
  loss_reduce_kernel<<<1, 1024, 0, stream>>>(row_loss, out_loss);
}